// Round 10
// baseline (93.025 us; speedup 1.0000x reference)
//
#include <hip/hip_runtime.h>

#define B_N 4096
#define D_K 256
#define BT  64                      // block tile (64x64)
#define NT  (B_N / BT)              // 64
#define NBLK (NT * (NT + 1) / 2)    // 2080 triangular blocks
#define BK  64                      // k-chunk (128 B/row)
#define NKITER (D_K / BK)           // 4

typedef __bf16 bf16x8 __attribute__((ext_vector_type(8)));
typedef float  floatx4 __attribute__((ext_vector_type(4)));

typedef __attribute__((address_space(3))) unsigned int lds_u32;
typedef const __attribute__((address_space(1))) unsigned int glb_u32;

__device__ inline unsigned short f2bf(float f) {
    unsigned int u = __float_as_uint(f);
    return (unsigned short)((u + 0x7FFFu + ((u >> 16) & 1u)) >> 16);
}

// ---------------------------------------------------------------------------
// prep: fp32 squared norms (exact), packed labels, bf16 copy of F,
//       and zero the completion counter used by pair's final reduction.
// ---------------------------------------------------------------------------
__global__ __launch_bounds__(256) void prep_kernel(const float* __restrict__ F,
                                                   const int* __restrict__ labels,
                                                   float* __restrict__ sq,
                                                   int* __restrict__ plab,
                                                   unsigned short* __restrict__ Fb,
                                                   unsigned int* __restrict__ counter) {
    if (blockIdx.x == 0 && threadIdx.x == 0) *counter = 0;
    int row  = blockIdx.x * 4 + (threadIdx.x >> 6);
    int lane = threadIdx.x & 63;
    const float4* fp = reinterpret_cast<const float4*>(F + (size_t)row * D_K);
    float4 v = fp[lane];
    ushort4 b;
    b.x = f2bf(v.x); b.y = f2bf(v.y); b.z = f2bf(v.z); b.w = f2bf(v.w);
    reinterpret_cast<ushort4*>(Fb + (size_t)row * D_K)[lane] = b;
    float s = v.x * v.x + v.y * v.y + v.z * v.z + v.w * v.w;
#pragma unroll
    for (int off = 32; off > 0; off >>= 1) s += __shfl_down(s, off);
    if (lane == 0) {
        sq[row] = s;
        const int* lp = labels + (size_t)row * 3;
        plab[row] = lp[0] | (lp[1] << 3) | (lp[2] << 6);
    }
}

// ---------------------------------------------------------------------------
// pair: 64x64 tile per 256-thread block (4 waves, 32x32 quadrant each).
// BK=64 DOUBLE-BUFFERED LDS (2 x 16 KB = 32 KB -> 5 blocks/CU, 20 waves/CU);
// ONE barrier per k-iter; stage(it+1) issued AFTER the barrier so the next
// barrier's vmcnt drain covers loads issued a full compute-phase earlier
// (structurally de-phased — attacks the lockstep stall of R9's 2-barrier loop).
// Staging layout (verified R4/R9): global_load_lds width-16, 128 B rows =
// 8 chunks, LDS(row,phys) holds global chunk phys^(row&7); 0 bank conflicts.
// C/D map (verified): col = lane&15, row = (lane>>4)*4 + reg.
// Tail: block partial via atomicExch (device scope), returned value consumed
// to force completion BEFORE the counter atomicAdd issues (ordering without
// fences); last block reads partials via atomicAdd(p, 0.0f) and writes out.
// ---------------------------------------------------------------------------
__global__ __launch_bounds__(256) void pair_kernel(const unsigned short* __restrict__ Fb,
                                                   const float* __restrict__ sq,
                                                   const int* __restrict__ plab,
                                                   float* __restrict__ partials,
                                                   unsigned int* __restrict__ counter,
                                                   float* __restrict__ out) {
    __shared__ unsigned short As[2][BT * BK];   // 2 x 8 KB
    __shared__ unsigned short Bs[2][BT * BK];   // 2 x 8 KB
    __shared__ float red[4];
    __shared__ bool  amLast;

    int idx = blockIdx.x, bi = 0;
    while (idx >= NT - bi) { idx -= NT - bi; ++bi; }
    const int bj = bi + idx;
    const bool diag = (bi == bj);

    const int i0   = bi * BT;
    const int j0   = bj * BT;
    const int wave = threadIdx.x >> 6;
    const int lane = threadIdx.x & 63;
    const int lrow = lane & 15;
    const int kgrp = lane >> 4;          // 0..3
    const int r0   = (wave >> 1) * 32;   // quadrant row
    const int c0   = (wave & 1) * 32;    // quadrant col

    floatx4 acc[2][2];
#pragma unroll
    for (int tm = 0; tm < 2; ++tm)
#pragma unroll
        for (int tn = 0; tn < 2; ++tn) acc[tm][tn] = floatx4{0.f, 0.f, 0.f, 0.f};

    const int srow_in = lane >> 3;       // 0..7 within one staging instr
    const int sphys   = lane & 7;        // physical 16B chunk within row

    const char* gA = (const char*)(Fb + (size_t)i0 * D_K);
    const char* gB = (const char*)(Fb + (size_t)j0 * D_K);

    // stage k-chunk `it` into buffer `buf`; 8 instrs per matrix, 2 per wave
    auto stage = [&](int it, int buf) {
        const size_t kbyte = (size_t)it * BK * 2;
        char* lAs = (char*)As[buf];
        char* lBs = (char*)Bs[buf];
#pragma unroll
        for (int q = 0; q < 2; ++q) {
            int instr = wave * 2 + q;               // 0..7
            int row   = instr * 8 + srow_in;        // 0..63
            int chunk = sphys ^ (row & 7);
            __builtin_amdgcn_global_load_lds(
                (glb_u32*)(gA + (size_t)row * (D_K * 2) + kbyte + chunk * 16),
                (lds_u32*)(lAs + instr * 1024), 16, 0, 0);
            if (!diag)
                __builtin_amdgcn_global_load_lds(
                    (glb_u32*)(gB + (size_t)row * (D_K * 2) + kbyte + chunk * 16),
                    (lds_u32*)(lBs + instr * 1024), 16, 0, 0);
        }
    };

    stage(0, 0);

    for (int it = 0; it < NKITER; ++it) {
        const int cur = it & 1;
        __syncthreads();                 // buf[cur] ready (its loads were
                                         // issued a full iter ago)
        if (it + 1 < NKITER) stage(it + 1, cur ^ 1);

        const char* cAs = (const char*)As[cur];
        const char* cBs = diag ? cAs : (const char*)Bs[cur];
#pragma unroll
        for (int ks = 0; ks < 2; ++ks) {
            bf16x8 a[2], b[2];
            const int c = ks * 4 + kgrp;            // logical chunk 0..7
#pragma unroll
            for (int tm = 0; tm < 2; ++tm) {
                int row = r0 + tm * 16 + lrow;
                a[tm] = *reinterpret_cast<const bf16x8*>(
                    cAs + row * 128 + ((c ^ (row & 7)) * 16));
            }
#pragma unroll
            for (int tn = 0; tn < 2; ++tn) {
                int row = c0 + tn * 16 + lrow;
                b[tn] = *reinterpret_cast<const bf16x8*>(
                    cBs + row * 128 + ((c ^ (row & 7)) * 16));
            }
#pragma unroll
            for (int tm = 0; tm < 2; ++tm)
#pragma unroll
                for (int tn = 0; tn < 2; ++tn)
                    acc[tm][tn] = __builtin_amdgcn_mfma_f32_16x16x32_bf16(
                        a[tm], b[tn], acc[tm][tn], 0, 0, 0);
        }
    }

    // epilogue: d2 = sq_i + sq_j - 2g; contrastive term; strict j>i mask
    float sqj[2];
    int   lj[2];
#pragma unroll
    for (int tn = 0; tn < 2; ++tn) {
        int j = j0 + c0 + tn * 16 + lrow;
        sqj[tn] = sq[j];
        lj[tn]  = plab[j];
    }

    float local = 0.f;
#pragma unroll
    for (int tm = 0; tm < 2; ++tm) {
#pragma unroll
        for (int r = 0; r < 4; ++r) {
            int i = i0 + r0 + tm * 16 + kgrp * 4 + r;
            float sqi = sq[i];
            int   li  = plab[i];
#pragma unroll
            for (int tn = 0; tn < 2; ++tn) {
                int j = j0 + c0 + tn * 16 + lrow;
                if (j > i) {
                    float d2 = fmaxf(sqi + sqj[tn] - 2.f * acc[tm][tn][r], 0.f);
                    float dist = sqrtf(d2);
                    local += (li == lj[tn]) ? (0.5f * dist)
                                            : (0.5f * fmaxf(1.f - dist, 0.f));
                }
            }
        }
    }

#pragma unroll
    for (int off = 32; off > 0; off >>= 1) local += __shfl_down(local, off);
    if (lane == 0) red[wave] = local;
    __syncthreads();

    // fence-free completion protocol
    if (threadIdx.x == 0) {
        float bsum = red[0] + red[1] + red[2] + red[3];
        float old = atomicExch(&partials[blockIdx.x], bsum);  // device-scope RMW
        __asm__ volatile("" : "+v"(old));   // consume -> vmcnt wait -> swap
                                            // complete before counter issues
        unsigned int done = atomicAdd(counter, 1u);
        amLast = (done == NBLK - 1);
    }
    __syncthreads();

    if (amLast) {
        float s = 0.f;
        for (int i = threadIdx.x; i < NBLK; i += 256)
            s += atomicAdd(&partials[i], 0.0f);   // coherent read at L2 point
#pragma unroll
        for (int off = 32; off > 0; off >>= 1) s += __shfl_down(s, off);
        if (lane == 0) red[wave] = s;
        __syncthreads();
        if (threadIdx.x == 0)
            out[0] = (red[0] + red[1] + red[2] + red[3]) * (1.0f / B_N);
    }
}

extern "C" void kernel_launch(void* const* d_in, const int* in_sizes, int n_in,
                              void* d_out, int out_size, void* d_ws, size_t ws_size,
                              hipStream_t stream) {
    const float* F      = (const float*)d_in[0];
    const int*   labels = (const int*)d_in[1];
    float* out = (float*)d_out;

    float*          sq    = (float*)d_ws;                                 // 16 KB
    int*            plab  = (int*)((char*)d_ws + B_N * 4);                // 16 KB
    float*          parts = (float*)((char*)d_ws + 2 * B_N * 4);          // 8.3 KB
    unsigned int*   cnt   = (unsigned int*)((char*)d_ws + 48 * 1024);     // 4 B
    unsigned short* Fb    = (unsigned short*)((char*)d_ws + 65536);       // 2 MB

    prep_kernel<<<B_N / 4, 256, 0, stream>>>(F, labels, sq, plab, Fb, cnt);
    pair_kernel<<<NBLK, 256, 0, stream>>>(Fb, sq, plab, parts, cnt, out);
}

// Round 11
// 74.739 us; speedup vs baseline: 1.2447x; 1.2447x over previous
//
#include <hip/hip_runtime.h>

#define B_N 4096
#define D_K 256
#define BT  64                      // block tile (64x64)
#define NT  (B_N / BT)              // 64
#define NBLK (NT * (NT + 1) / 2)    // 2080 triangular blocks
#define BK  64                      // k-chunk (128 B/row)
#define NKITER (D_K / BK)           // 4

typedef __bf16 bf16x8 __attribute__((ext_vector_type(8)));
typedef float  floatx4 __attribute__((ext_vector_type(4)));

typedef __attribute__((address_space(3))) unsigned int lds_u32;
typedef const __attribute__((address_space(1))) unsigned int glb_u32;

__device__ inline unsigned short f2bf(float f) {
    unsigned int u = __float_as_uint(f);
    return (unsigned short)((u + 0x7FFFu + ((u >> 16) & 1u)) >> 16);
}

// ---------------------------------------------------------------------------
// prep: fp32 squared norms (exact), packed labels, bf16 copy of F.
// ---------------------------------------------------------------------------
__global__ __launch_bounds__(256) void prep_kernel(const float* __restrict__ F,
                                                   const int* __restrict__ labels,
                                                   float* __restrict__ sq,
                                                   int* __restrict__ plab,
                                                   unsigned short* __restrict__ Fb) {
    int row  = blockIdx.x * 4 + (threadIdx.x >> 6);
    int lane = threadIdx.x & 63;
    const float4* fp = reinterpret_cast<const float4*>(F + (size_t)row * D_K);
    float4 v = fp[lane];
    ushort4 b;
    b.x = f2bf(v.x); b.y = f2bf(v.y); b.z = f2bf(v.z); b.w = f2bf(v.w);
    reinterpret_cast<ushort4*>(Fb + (size_t)row * D_K)[lane] = b;
    float s = v.x * v.x + v.y * v.y + v.z * v.z + v.w * v.w;
#pragma unroll
    for (int off = 32; off > 0; off >>= 1) s += __shfl_down(s, off);
    if (lane == 0) {
        sq[row] = s;
        const int* lp = labels + (size_t)row * 3;
        plab[row] = lp[0] | (lp[1] << 3) | (lp[2] << 6);
    }
}

// ---------------------------------------------------------------------------
// pair: R9 structure (best: 75.5 us). 64x64 tile per 256-thread block,
// 4 waves x 32x32 quadrant, 16 KB single-buffered LDS, 2-barrier k-iter.
// TLP is the protection: ~8 blocks/CU co-resident so one block's barrier
// drain overlaps other blocks' compute (m114). Double-buffering regressed
// twice (R7 +7us, R10 +17.5us) — do not reintroduce. Same-address atomic
// tails regressed twice (R2 ~+50us, R10) — keep the separate reduce kernel.
// R11 deltas vs R9: __launch_bounds__(256,8) to force <=64 VGPR (8 blocks/CU
// vs 7 at VGPR=72), closed-form triangular decode (drops ~32-iter scalar loop).
// Staging (verified): global_load_lds width-16, 128 B rows = 8 chunks,
// LDS(row,phys) holds chunk phys^(row&7) -> 0 bank conflicts.
// C/D map (verified): col = lane&15, row = (lane>>4)*4 + reg.
// ---------------------------------------------------------------------------
__global__ __launch_bounds__(256, 8) void pair_kernel(const unsigned short* __restrict__ Fb,
                                                      const float* __restrict__ sq,
                                                      const int* __restrict__ plab,
                                                      float* __restrict__ partials) {
    __shared__ unsigned short smem[2 * BT * BK];   // A: 8 KB, B: 8 KB
    __shared__ float red[4];

    // closed-form triangular decode: idx = bi*NT - bi*(bi-1)/2 + (bj-bi)
    const float fidx = (float)blockIdx.x;
    int bi = (int)(((float)(2 * NT) + 1.0f -
                    sqrtf(((float)(2 * NT) + 1.0f) * ((float)(2 * NT) + 1.0f) -
                          8.0f * fidx)) * 0.5f);
    // guard fp rounding
    while (bi * NT - (bi * (bi - 1)) / 2 + (NT - bi) <= (int)blockIdx.x) ++bi;
    while (bi * NT - (bi * (bi - 1)) / 2 > (int)blockIdx.x) --bi;
    const int bj = bi + ((int)blockIdx.x - (bi * NT - (bi * (bi - 1)) / 2));
    const bool diag = (bi == bj);

    const int i0   = bi * BT;
    const int j0   = bj * BT;
    const int wave = threadIdx.x >> 6;
    const int lane = threadIdx.x & 63;
    const int lrow = lane & 15;
    const int kgrp = lane >> 4;          // 0..3
    const int r0   = (wave >> 1) * 32;   // quadrant row
    const int c0   = (wave & 1) * 32;    // quadrant col

    char* lAs = (char*)smem;
    char* lBs = diag ? lAs : (char*)(smem + BT * BK);

    floatx4 acc[2][2];
#pragma unroll
    for (int tm = 0; tm < 2; ++tm)
#pragma unroll
        for (int tn = 0; tn < 2; ++tn) acc[tm][tn] = floatx4{0.f, 0.f, 0.f, 0.f};

    const int srow_in = lane >> 3;       // 0..7 within one staging instr
    const int sphys   = lane & 7;        // physical 16B chunk within row

    const char* gA = (const char*)(Fb + (size_t)i0 * D_K);
    const char* gB = (const char*)(Fb + (size_t)j0 * D_K);

    for (int it = 0; it < NKITER; ++it) {
        const size_t kbyte = (size_t)it * BK * 2;   // 128 B per row per chunk
#pragma unroll
        for (int q = 0; q < 2; ++q) {
            int instr = wave * 2 + q;               // 0..7
            int row   = instr * 8 + srow_in;        // 0..63
            int chunk = sphys ^ (row & 7);
            __builtin_amdgcn_global_load_lds(
                (glb_u32*)(gA + (size_t)row * (D_K * 2) + kbyte + chunk * 16),
                (lds_u32*)(lAs + instr * 1024), 16, 0, 0);
            if (!diag)
                __builtin_amdgcn_global_load_lds(
                    (glb_u32*)(gB + (size_t)row * (D_K * 2) + kbyte + chunk * 16),
                    (lds_u32*)(lBs + instr * 1024), 16, 0, 0);
        }
        __syncthreads();

#pragma unroll
        for (int ks = 0; ks < 2; ++ks) {
            bf16x8 a[2], b[2];
            const int c = ks * 4 + kgrp;            // logical chunk 0..7
#pragma unroll
            for (int tm = 0; tm < 2; ++tm) {
                int row = r0 + tm * 16 + lrow;
                a[tm] = *reinterpret_cast<const bf16x8*>(
                    lAs + row * 128 + ((c ^ (row & 7)) * 16));
            }
#pragma unroll
            for (int tn = 0; tn < 2; ++tn) {
                int row = c0 + tn * 16 + lrow;
                b[tn] = *reinterpret_cast<const bf16x8*>(
                    lBs + row * 128 + ((c ^ (row & 7)) * 16));
            }
#pragma unroll
            for (int tm = 0; tm < 2; ++tm)
#pragma unroll
                for (int tn = 0; tn < 2; ++tn)
                    acc[tm][tn] = __builtin_amdgcn_mfma_f32_16x16x32_bf16(
                        a[tm], b[tn], acc[tm][tn], 0, 0, 0);
        }
        __syncthreads();
    }

    // epilogue: d2 = sq_i + sq_j - 2g; contrastive term; strict j>i mask
    float sqj[2];
    int   lj[2];
#pragma unroll
    for (int tn = 0; tn < 2; ++tn) {
        int j = j0 + c0 + tn * 16 + lrow;
        sqj[tn] = sq[j];
        lj[tn]  = plab[j];
    }

    float local = 0.f;
#pragma unroll
    for (int tm = 0; tm < 2; ++tm) {
#pragma unroll
        for (int r = 0; r < 4; ++r) {
            int i = i0 + r0 + tm * 16 + kgrp * 4 + r;
            float sqi = sq[i];
            int   li  = plab[i];
#pragma unroll
            for (int tn = 0; tn < 2; ++tn) {
                int j = j0 + c0 + tn * 16 + lrow;
                if (j > i) {
                    float d2 = fmaxf(sqi + sqj[tn] - 2.f * acc[tm][tn][r], 0.f);
                    float dist = sqrtf(d2);
                    local += (li == lj[tn]) ? (0.5f * dist)
                                            : (0.5f * fmaxf(1.f - dist, 0.f));
                }
            }
        }
    }

#pragma unroll
    for (int off = 32; off > 0; off >>= 1) local += __shfl_down(local, off);
    if (lane == 0) red[wave] = local;
    __syncthreads();
    if (threadIdx.x == 0)
        partials[blockIdx.x] = red[0] + red[1] + red[2] + red[3];
}

// ---------------------------------------------------------------------------
// reduce: 2080 partials -> out[0]
// ---------------------------------------------------------------------------
__global__ __launch_bounds__(256) void reduce_kernel(const float* __restrict__ partials,
                                                     float* __restrict__ out) {
    __shared__ float red[4];
    float s = 0.f;
    for (int i = threadIdx.x; i < NBLK; i += 256) s += partials[i];
#pragma unroll
    for (int off = 32; off > 0; off >>= 1) s += __shfl_down(s, off);
    if ((threadIdx.x & 63) == 0) red[threadIdx.x >> 6] = s;
    __syncthreads();
    if (threadIdx.x == 0)
        out[0] = (red[0] + red[1] + red[2] + red[3]) * (1.0f / B_N);
}

extern "C" void kernel_launch(void* const* d_in, const int* in_sizes, int n_in,
                              void* d_out, int out_size, void* d_ws, size_t ws_size,
                              hipStream_t stream) {
    const float* F      = (const float*)d_in[0];
    const int*   labels = (const int*)d_in[1];
    float* out = (float*)d_out;

    float*          sq    = (float*)d_ws;                                 // 16 KB
    int*            plab  = (int*)((char*)d_ws + B_N * 4);                // 16 KB
    float*          parts = (float*)((char*)d_ws + 2 * B_N * 4);          // ~8.3 KB
    unsigned short* Fb    = (unsigned short*)((char*)d_ws + 65536);       // 2 MB

    prep_kernel<<<B_N / 4, 256, 0, stream>>>(F, labels, sq, plab, Fb);
    pair_kernel<<<NBLK, 256, 0, stream>>>(Fb, sq, plab, parts);
    reduce_kernel<<<1, 256, 0, stream>>>(parts, out);
}

// Round 12
// 73.574 us; speedup vs baseline: 1.2644x; 1.0158x over previous
//
#include <hip/hip_runtime.h>

#define B_N 4096
#define D_K 256
#define BT  64                      // block tile (64x64)
#define NT  (B_N / BT)              // 64
#define NBLK (NT * (NT + 1) / 2)    // 2080 triangular blocks
#define BK  128                     // k-chunk (128 B/row in fp8)
#define NKITER (D_K / BK)           // 2

typedef float floatx4 __attribute__((ext_vector_type(4)));

typedef __attribute__((address_space(3))) unsigned int lds_u32;
typedef const __attribute__((address_space(1))) unsigned int glb_u32;

// ---------------------------------------------------------------------------
// prep: fp32 squared norms (exact), packed labels, fp8 e4m3 copy of F.
// One wave per row: lane holds float4, packs to 4 fp8 bytes -> 1 uint store.
// ---------------------------------------------------------------------------
__global__ __launch_bounds__(256) void prep_kernel(const float* __restrict__ F,
                                                   const int* __restrict__ labels,
                                                   float* __restrict__ sq,
                                                   int* __restrict__ plab,
                                                   unsigned int* __restrict__ F8) {
    int row  = blockIdx.x * 4 + (threadIdx.x >> 6);
    int lane = threadIdx.x & 63;
    const float4* fp = reinterpret_cast<const float4*>(F + (size_t)row * D_K);
    float4 v = fp[lane];
    unsigned int p = 0;
    p = __builtin_amdgcn_cvt_pk_fp8_f32(v.x, v.y, p, false);  // bytes 0,1
    p = __builtin_amdgcn_cvt_pk_fp8_f32(v.z, v.w, p, true);   // bytes 2,3
    F8[(size_t)row * (D_K / 4) + lane] = p;
    float s = v.x * v.x + v.y * v.y + v.z * v.z + v.w * v.w;
#pragma unroll
    for (int off = 32; off > 0; off >>= 1) s += __shfl_down(s, off);
    if (lane == 0) {
        sq[row] = s;
        const int* lp = labels + (size_t)row * 3;
        plab[row] = lp[0] | (lp[1] << 3) | (lp[2] << 6);
    }
}

// ---------------------------------------------------------------------------
// pair: R9/R11 structure (best known), fp8 data path.
// 64x64 tile per 256-thread block, 4 waves x 32x32 quadrant, single-buffered
// LDS (2 x 8 KB), 2-barrier k-iter, ~8 blocks/CU TLP (the proven protection;
// dbuf regressed twice, atomic tails regressed twice — do not reintroduce).
// fp8 @ BK=128 reproduces the VERIFIED bf16 BK=64 byte geometry exactly:
// 64 rows x 128 B, 8 chunks/row, LDS(row,phys) holds chunk phys^(row&7),
// staging = global_load_lds width-16, 2 instrs/wave/matrix/iter.
// Frag: mfma_f32_16x16x32_fp8_fp8, A/B = 8 B/lane: logical byte
// ks*32+kgrp*8 -> chunk c=ks*2+(kgrp>>1), half=kgrp&1 -> ds_read_b64 at
// row*128 + (c^(row&7))*16 + half*8 (bank spread exactly even, checked).
// C/D map (shape-determined, verified): col=lane&15, row=(lane>>4)*4+reg.
// NKITER=2 -> 4 barrier crossings/block (was 8).
// ---------------------------------------------------------------------------
__global__ __launch_bounds__(256, 8) void pair_kernel(const unsigned char* __restrict__ F8,
                                                      const float* __restrict__ sq,
                                                      const int* __restrict__ plab,
                                                      float* __restrict__ partials) {
    __shared__ char smem[2 * BT * BK];   // A: 8 KB, B: 8 KB
    __shared__ float red[4];

    // closed-form triangular decode (R11-verified)
    const float fidx = (float)blockIdx.x;
    int bi = (int)(((float)(2 * NT) + 1.0f -
                    sqrtf(((float)(2 * NT) + 1.0f) * ((float)(2 * NT) + 1.0f) -
                          8.0f * fidx)) * 0.5f);
    while (bi * NT - (bi * (bi - 1)) / 2 + (NT - bi) <= (int)blockIdx.x) ++bi;
    while (bi * NT - (bi * (bi - 1)) / 2 > (int)blockIdx.x) --bi;
    const int bj = bi + ((int)blockIdx.x - (bi * NT - (bi * (bi - 1)) / 2));
    const bool diag = (bi == bj);

    const int i0   = bi * BT;
    const int j0   = bj * BT;
    const int wave = threadIdx.x >> 6;
    const int lane = threadIdx.x & 63;
    const int lrow = lane & 15;
    const int kgrp = lane >> 4;          // 0..3
    const int r0   = (wave >> 1) * 32;   // quadrant row
    const int c0   = (wave & 1) * 32;    // quadrant col

    char* lAs = smem;
    char* lBs = diag ? lAs : (smem + BT * BK);

    floatx4 acc[2][2];
#pragma unroll
    for (int tm = 0; tm < 2; ++tm)
#pragma unroll
        for (int tn = 0; tn < 2; ++tn) acc[tm][tn] = floatx4{0.f, 0.f, 0.f, 0.f};

    const int srow_in = lane >> 3;       // 0..7 within one staging instr
    const int sphys   = lane & 7;        // physical 16B chunk within row

    const char* gA = (const char*)F8 + (size_t)i0 * D_K;   // fp8: row = 256 B
    const char* gB = (const char*)F8 + (size_t)j0 * D_K;

    const int half8 = (kgrp & 1) * 8;    // byte offset within 16B chunk
    const int chalf = kgrp >> 1;         // chunk half-index

    for (int it = 0; it < NKITER; ++it) {
        const size_t kbyte = (size_t)it * BK;       // 128 B per row per iter
#pragma unroll
        for (int q = 0; q < 2; ++q) {
            int instr = wave * 2 + q;               // 0..7
            int row   = instr * 8 + srow_in;        // 0..63
            int chunk = sphys ^ (row & 7);
            __builtin_amdgcn_global_load_lds(
                (glb_u32*)(gA + (size_t)row * D_K + kbyte + chunk * 16),
                (lds_u32*)(lAs + instr * 1024), 16, 0, 0);
            if (!diag)
                __builtin_amdgcn_global_load_lds(
                    (glb_u32*)(gB + (size_t)row * D_K + kbyte + chunk * 16),
                    (lds_u32*)(lBs + instr * 1024), 16, 0, 0);
        }
        __syncthreads();

#pragma unroll
        for (int ks = 0; ks < 4; ++ks) {
            long a[2], b[2];
            const int c = ks * 2 + chalf;           // logical chunk 0..7
#pragma unroll
            for (int tm = 0; tm < 2; ++tm) {
                int row = r0 + tm * 16 + lrow;
                a[tm] = *reinterpret_cast<const long*>(
                    lAs + row * 128 + ((c ^ (row & 7)) * 16) + half8);
            }
#pragma unroll
            for (int tn = 0; tn < 2; ++tn) {
                int row = c0 + tn * 16 + lrow;
                b[tn] = *reinterpret_cast<const long*>(
                    lBs + row * 128 + ((c ^ (row & 7)) * 16) + half8);
            }
#pragma unroll
            for (int tm = 0; tm < 2; ++tm)
#pragma unroll
                for (int tn = 0; tn < 2; ++tn)
                    acc[tm][tn] = __builtin_amdgcn_mfma_f32_16x16x32_fp8_fp8(
                        a[tm], b[tn], acc[tm][tn], 0, 0, 0);
        }
        __syncthreads();
    }

    // epilogue: d2 = sq_i + sq_j - 2g; contrastive term; strict j>i mask
    float sqj[2];
    int   lj[2];
#pragma unroll
    for (int tn = 0; tn < 2; ++tn) {
        int j = j0 + c0 + tn * 16 + lrow;
        sqj[tn] = sq[j];
        lj[tn]  = plab[j];
    }

    float local = 0.f;
#pragma unroll
    for (int tm = 0; tm < 2; ++tm) {
#pragma unroll
        for (int r = 0; r < 4; ++r) {
            int i = i0 + r0 + tm * 16 + kgrp * 4 + r;
            float sqi = sq[i];
            int   li  = plab[i];
#pragma unroll
            for (int tn = 0; tn < 2; ++tn) {
                int j = j0 + c0 + tn * 16 + lrow;
                if (j > i) {
                    float d2 = fmaxf(sqi + sqj[tn] - 2.f * acc[tm][tn][r], 0.f);
                    float dist = sqrtf(d2);
                    local += (li == lj[tn]) ? (0.5f * dist)
                                            : (0.5f * fmaxf(1.f - dist, 0.f));
                }
            }
        }
    }

#pragma unroll
    for (int off = 32; off > 0; off >>= 1) local += __shfl_down(local, off);
    if (lane == 0) red[wave] = local;
    __syncthreads();
    if (threadIdx.x == 0)
        partials[blockIdx.x] = red[0] + red[1] + red[2] + red[3];
}

// ---------------------------------------------------------------------------
// reduce: 2080 partials -> out[0]
// ---------------------------------------------------------------------------
__global__ __launch_bounds__(256) void reduce_kernel(const float* __restrict__ partials,
                                                     float* __restrict__ out) {
    __shared__ float red[4];
    float s = 0.f;
    for (int i = threadIdx.x; i < NBLK; i += 256) s += partials[i];
#pragma unroll
    for (int off = 32; off > 0; off >>= 1) s += __shfl_down(s, off);
    if ((threadIdx.x & 63) == 0) red[threadIdx.x >> 6] = s;
    __syncthreads();
    if (threadIdx.x == 0)
        out[0] = (red[0] + red[1] + red[2] + red[3]) * (1.0f / B_N);
}

extern "C" void kernel_launch(void* const* d_in, const int* in_sizes, int n_in,
                              void* d_out, int out_size, void* d_ws, size_t ws_size,
                              hipStream_t stream) {
    const float* F      = (const float*)d_in[0];
    const int*   labels = (const int*)d_in[1];
    float* out = (float*)d_out;

    float*        sq    = (float*)d_ws;                                 // 16 KB
    int*          plab  = (int*)((char*)d_ws + B_N * 4);                // 16 KB
    float*        parts = (float*)((char*)d_ws + 2 * B_N * 4);          // ~8.3 KB
    unsigned int* F8    = (unsigned int*)((char*)d_ws + 65536);         // 1 MB fp8

    prep_kernel<<<B_N / 4, 256, 0, stream>>>(F, labels, sq, plab, F8);
    pair_kernel<<<NBLK, 256, 0, stream>>>((const unsigned char*)F8, sq, plab, parts);
    reduce_kernel<<<1, 256, 0, stream>>>(parts, out);
}